// Round 1
// baseline (659.018 us; speedup 1.0000x reference)
//
#include <hip/hip_runtime.h>
#include <hip/hip_bf16.h>

#define N_NODES 50000
#define E_EDGES 400000
#define IN_CH   256
#define HEADS   4
#define OUT_CH  64
#define HID     256
#define ALPHA   0.2f
#define LN_EPS  1e-5f

// ---------------------------------------------------------------- utilities
__device__ __forceinline__ void atomicMaxFloat(float* addr, float val) {
    if (val >= 0.f) atomicMax((int*)addr, __float_as_int(val));
    else            atomicMin((unsigned int*)addr, __float_as_uint(val));
}

// ---------------------------------------------------------------- init
__global__ void init_kernel(float* __restrict__ gmax) {
    if (threadIdx.x < HEADS) gmax[threadIdx.x] = -3.402823466e38f;
}

// ---------------------------------------------------------------- f32 GEMM
// C[M,N] = A[M,K] @ B[K,N] (+bias, relu).  BM=BN=64, BK=16, 256 thr, 4x4/thr.
template<bool RELU_BIAS>
__global__ __launch_bounds__(256) void gemm_f32(
    const float* __restrict__ A, const float* __restrict__ B,
    const float* __restrict__ bias, float* __restrict__ C,
    int M, int K, int N)
{
    const int BM = 64, BN = 64, BK = 16;
    __shared__ float As[BK][BM + 4];  // A^T tile, padded (16B-aligned rows)
    __shared__ float Bs[BK][BN + 4];

    const int ntn = N / BN;
    const int bx = blockIdx.x % ntn;
    const int by = blockIdx.x / ntn;
    const int row0 = by * BM, col0 = bx * BN;
    const int tid = threadIdx.x;
    const int tx = tid & 15, ty = tid >> 4;

    float acc[4][4] = {};
    for (int k0 = 0; k0 < K; k0 += BK) {
        #pragma unroll
        for (int i = 0; i < 4; i++) {
            int idx = tid + i * 256;          // 0..1023
            int r = idx >> 4, c = idx & 15;   // 64 x 16
            int gr = row0 + r;
            As[c][r] = (gr < M) ? A[gr * K + k0 + c] : 0.f;
        }
        #pragma unroll
        for (int i = 0; i < 4; i++) {
            int idx = tid + i * 256;
            int r = idx >> 6, c = idx & 63;   // 16 x 64
            Bs[r][c] = B[(k0 + r) * N + col0 + c];
        }
        __syncthreads();
        #pragma unroll
        for (int kk = 0; kk < BK; kk++) {
            float a[4], b[4];
            #pragma unroll
            for (int i = 0; i < 4; i++) a[i] = As[kk][ty * 4 + i];
            #pragma unroll
            for (int j = 0; j < 4; j++) b[j] = Bs[kk][tx * 4 + j];
            #pragma unroll
            for (int i = 0; i < 4; i++)
                #pragma unroll
                for (int j = 0; j < 4; j++)
                    acc[i][j] += a[i] * b[j];
        }
        __syncthreads();
    }
    #pragma unroll
    for (int i = 0; i < 4; i++) {
        int gr = row0 + ty * 4 + i;
        if (gr >= M) continue;
        #pragma unroll
        for (int j = 0; j < 4; j++) {
            int gc = col0 + tx * 4 + j;
            float v = acc[i][j];
            if (RELU_BIAS) { v += bias[gc]; v = v > 0.f ? v : 0.f; }
            C[gr * N + gc] = v;
        }
    }
}

// ---------------------------------------------------------------- node scores
// s_src[n,h] = dot(Wh[n,h,:], attn_fc[h, :64]);  s_dst uses attn_fc[h, 64:]
__global__ __launch_bounds__(256) void scores_kernel(
    const float* __restrict__ Wh, const float* __restrict__ attn_fc,
    float* __restrict__ s_src, float* __restrict__ s_dst)
{
    const int n = blockIdx.x;
    const int t = threadIdx.x;
    const int h = t >> 6, d = t & 63;
    float w = Wh[n * HID + t];
    float ps = w * attn_fc[h * 2 * OUT_CH + d];
    float pd = w * attn_fc[h * 2 * OUT_CH + OUT_CH + d];
    #pragma unroll
    for (int off = 32; off; off >>= 1) {
        ps += __shfl_xor(ps, off, 64);
        pd += __shfl_xor(pd, off, 64);
    }
    if (d == 0) {
        s_src[n * HEADS + h] = ps;
        s_dst[n * HEADS + h] = pd;
    }
}

// ---------------------------------------------------------------- global max per head
__global__ __launch_bounds__(256) void edge_max_kernel(
    const int* __restrict__ erow, const int* __restrict__ ecol,
    const float* __restrict__ s_src, const float* __restrict__ s_dst,
    float* __restrict__ gmax)
{
    float m[HEADS] = {-3.4e38f, -3.4e38f, -3.4e38f, -3.4e38f};
    for (int e = blockIdx.x * blockDim.x + threadIdx.x; e < E_EDGES;
         e += gridDim.x * blockDim.x) {
        int r = erow[e], c = ecol[e];
        float4 ss = ((const float4*)s_src)[r];
        float4 sd = ((const float4*)s_dst)[c];
        float sc[HEADS] = {ss.x + sd.x, ss.y + sd.y, ss.z + sd.z, ss.w + sd.w};
        #pragma unroll
        for (int h = 0; h < HEADS; h++) {
            float v = sc[h] > 0.f ? sc[h] : ALPHA * sc[h];
            m[h] = fmaxf(m[h], v);
        }
    }
    #pragma unroll
    for (int h = 0; h < HEADS; h++) {
        #pragma unroll
        for (int off = 32; off; off >>= 1)
            m[h] = fmaxf(m[h], __shfl_xor(m[h], off, 64));
    }
    if ((threadIdx.x & 63) == 0) {
        #pragma unroll
        for (int h = 0; h < HEADS; h++) atomicMaxFloat(&gmax[h], m[h]);
    }
}

// ---------------------------------------------------------------- CSR build
__global__ void hist_kernel(const int* __restrict__ erow, int* __restrict__ counts) {
    int e = blockIdx.x * blockDim.x + threadIdx.x;
    if (e < E_EDGES) atomicAdd(&counts[erow[e]], 1);
}

__global__ __launch_bounds__(1024) void scan_kernel(
    const int* __restrict__ counts, int* __restrict__ offsets, int* __restrict__ cursor)
{
    __shared__ int wsum[16];
    __shared__ int carry_s;
    const int tid = threadIdx.x;
    const int lane = tid & 63, wid = tid >> 6;
    if (tid == 0) carry_s = 0;
    __syncthreads();
    for (int base = 0; base < N_NODES; base += 1024) {
        int i = base + tid;
        int v = (i < N_NODES) ? counts[i] : 0;
        int x = v;
        #pragma unroll
        for (int off = 1; off < 64; off <<= 1) {
            int y = __shfl_up(x, off, 64);
            if (lane >= off) x += y;
        }
        if (lane == 63) wsum[wid] = x;
        __syncthreads();
        if (wid == 0) {
            int s = (lane < 16) ? wsum[lane] : 0;
            #pragma unroll
            for (int off = 1; off < 16; off <<= 1) {
                int y = __shfl_up(s, off, 64);
                if (lane >= off) s += y;
            }
            if (lane < 16) wsum[lane] = s;
        }
        __syncthreads();
        int carry = carry_s;
        int prefix = carry + (wid ? wsum[wid - 1] : 0);
        int excl = prefix + x - v;
        if (i < N_NODES) { offsets[i] = excl; cursor[i] = excl; }
        __syncthreads();
        if (tid == 0) carry_s = carry + wsum[15];
        __syncthreads();
    }
    if (tid == 0) offsets[N_NODES] = carry_s;
}

__global__ void scatter_kernel(const int* __restrict__ erow, const int* __restrict__ ecol,
                               int* __restrict__ cursor, int* __restrict__ sorted_col) {
    int e = blockIdx.x * blockDim.x + threadIdx.x;
    if (e >= E_EDGES) return;
    int r = erow[e];
    int pos = atomicAdd(&cursor[r], 1);
    sorted_col[pos] = ecol[e];
}

// ---------------------------------------------------------------- aggregate + residual + LN
__global__ __launch_bounds__(256) void aggregate_ln_kernel(
    const float* __restrict__ Wh, const float* __restrict__ s_src,
    const float* __restrict__ s_dst, const float* __restrict__ gmax,
    const int* __restrict__ offsets, const int* __restrict__ sorted_col,
    const float* __restrict__ ln_gamma, const float* __restrict__ ln_beta,
    float* __restrict__ h_ln)
{
    const int n = blockIdx.x;
    const int t = threadIdx.x;
    const int h = t >> 6;
    const float ssrc = s_src[n * HEADS + h];
    const float gm = gmax[h];
    const int beg = offsets[n], end = offsets[n + 1];

    float acc = 0.f, wsumv = 0.f;
    for (int j = beg; j < end; j++) {
        int c = sorted_col[j];
        float sc = ssrc + s_dst[c * HEADS + h];
        sc = sc > 0.f ? sc : ALPHA * sc;
        float w = __expf(sc - gm);
        wsumv += w;
        acc += w * Wh[c * HID + t];
    }
    float val = acc / (wsumv + 1e-15f) + Wh[n * HID + t];

    __shared__ float red[4];
    float s = val;
    #pragma unroll
    for (int off = 32; off; off >>= 1) s += __shfl_xor(s, off, 64);
    if ((t & 63) == 0) red[t >> 6] = s;
    __syncthreads();
    float mu = (red[0] + red[1] + red[2] + red[3]) * (1.f / HID);
    __syncthreads();
    float dv = val - mu;
    float s2 = dv * dv;
    #pragma unroll
    for (int off = 32; off; off >>= 1) s2 += __shfl_xor(s2, off, 64);
    if ((t & 63) == 0) red[t >> 6] = s2;
    __syncthreads();
    float var = (red[0] + red[1] + red[2] + red[3]) * (1.f / HID);
    float outv = dv * rsqrtf(var + LN_EPS) * ln_gamma[t] + ln_beta[t];
    h_ln[n * HID + t] = outv;
}

// ---------------------------------------------------------------- launch
extern "C" void kernel_launch(void* const* d_in, const int* in_sizes, int n_in,
                              void* d_out, int out_size, void* d_ws, size_t ws_size,
                              hipStream_t stream)
{
    const float* h        = (const float*)d_in[0];
    const int*   erow     = (const int*)  d_in[1];
    const int*   ecol     = (const int*)  d_in[2];
    const float* W        = (const float*)d_in[3];
    const float* attn_fc  = (const float*)d_in[4];
    const float* ln_gamma = (const float*)d_in[5];
    const float* ln_beta  = (const float*)d_in[6];
    const float* ffn_w    = (const float*)d_in[7];
    const float* ffn_b    = (const float*)d_in[8];
    float* out = (float*)d_out;

    // workspace layout (all f32/int32, 4B elems)
    float* Wh       = (float*)d_ws;                 // N*HID
    float* h_ln     = Wh + (size_t)N_NODES * HID;   // N*HID
    float* s_src    = h_ln + (size_t)N_NODES * HID; // N*HEADS
    float* s_dst    = s_src + N_NODES * HEADS;      // N*HEADS
    float* gmax     = s_dst + N_NODES * HEADS;      // 64 (padded)
    int*   counts   = (int*)(gmax + 64);            // N
    int*   offsets  = counts + N_NODES;             // N+1
    int*   cursor   = offsets + N_NODES + 1;        // N
    int*   sorted_col = cursor + N_NODES;           // E

    hipMemsetAsync(counts, 0, N_NODES * sizeof(int), stream);
    init_kernel<<<1, 64, 0, stream>>>(gmax);

    // Wh = h @ W
    {
        int gm_ = ((N_NODES + 63) / 64) * (HID / 64);
        gemm_f32<false><<<gm_, 256, 0, stream>>>(h, W, nullptr, Wh, N_NODES, IN_CH, HID);
    }
    scores_kernel<<<N_NODES, 256, 0, stream>>>(Wh, attn_fc, s_src, s_dst);
    hist_kernel<<<(E_EDGES + 255) / 256, 256, 0, stream>>>(erow, counts);
    edge_max_kernel<<<512, 256, 0, stream>>>(erow, ecol, s_src, s_dst, gmax);
    scan_kernel<<<1, 1024, 0, stream>>>(counts, offsets, cursor);
    scatter_kernel<<<(E_EDGES + 255) / 256, 256, 0, stream>>>(erow, ecol, cursor, sorted_col);
    aggregate_ln_kernel<<<N_NODES, 256, 0, stream>>>(Wh, s_src, s_dst, gmax,
                                                     offsets, sorted_col,
                                                     ln_gamma, ln_beta, h_ln);
    // out = relu(h_ln @ ffn_w + b)
    {
        int gm_ = ((N_NODES + 63) / 64) * (HID / 64);
        gemm_f32<true><<<gm_, 256, 0, stream>>>(h_ln, ffn_w, ffn_b, out, N_NODES, HID, HID);
    }
}

// Round 2
// 374.402 us; speedup vs baseline: 1.7602x; 1.7602x over previous
//
#include <hip/hip_runtime.h>
#include <hip/hip_bf16.h>

#define N_NODES 50000
#define E_EDGES 400000
#define IN_CH   256
#define HEADS   4
#define OUT_CH  64
#define HID     256
#define ALPHA   0.2f
#define LN_EPS  1e-5f

using f32x4  = __attribute__((ext_vector_type(4))) float;
using bf16x8 = __attribute__((ext_vector_type(8))) short;   // 8 bf16 (4 VGPRs)
using u16x8  = __attribute__((ext_vector_type(8))) unsigned short;
using u16x4  = __attribute__((ext_vector_type(4))) unsigned short;

__device__ __forceinline__ unsigned short f2bf(float f) {
    __hip_bfloat16 b = __float2bfloat16(f);
    return *(unsigned short*)&b;
}
__device__ __forceinline__ float bf2f(unsigned short u) {
    __hip_bfloat16 b = *(__hip_bfloat16*)&u;
    return __bfloat162float(b);
}
__device__ __forceinline__ void atomicMaxFloat(float* addr, float val) {
    if (val >= 0.f) atomicMax((int*)addr, __float_as_int(val));
    else            atomicMin((unsigned int*)addr, __float_as_uint(val));
}

// ------------------------------------------------------------------ prep
// Wt[n][k] = bf16(W[k][n]); Ft[n][k] = bf16(ffn_w[k][n]); init gmax.
__global__ __launch_bounds__(256) void prep_kernel(
    const float* __restrict__ W, const float* __restrict__ ffn_w,
    unsigned short* __restrict__ Wt, unsigned short* __restrict__ Ft,
    float* __restrict__ gmax)
{
    int i = blockIdx.x * 256 + threadIdx.x;
    if (i < 65536) {
        int n = i >> 8, k = i & 255;
        Wt[i] = f2bf(W[k * 256 + n]);
    } else {
        int j = i - 65536;
        int n = j >> 8, k = j & 255;
        Ft[j] = f2bf(ffn_w[k * 256 + n]);
    }
    if (blockIdx.x == 0 && threadIdx.x < HEADS) gmax[threadIdx.x] = -3.402823466e38f;
}

// ------------------------------------------------------------------ MFMA GEMM
// C[M,256] = A[M,256] @ B[256,256], B given pre-transposed bf16 Bt[N][K].
// BM=128, BN=128, BK=64; 256 thr = 4 waves (2x2), wave-tile 64x64.
// A_IS_F32: A is f32, converted to bf16 during staging; else A is bf16.
// RELU_BIAS: C = relu(acc + bias), f32 out;  else C = bf16(acc).
template<bool A_IS_F32, bool RELU_BIAS>
__global__ __launch_bounds__(256) void gemm_mfma(
    const void* __restrict__ Av, const unsigned short* __restrict__ Bt,
    const float* __restrict__ bias, void* __restrict__ Cv, int M)
{
    constexpr int K = 256, BM = 128, BK = 64;
    __shared__ unsigned short As[BM * BK];   // row-major [128][64], XOR-swizzled
    __shared__ unsigned short Bs[BM * BK];   // Bt rows   [128][64], XOR-swizzled

    const int bx = blockIdx.x & 1;           // N/BN = 2
    const int by = blockIdx.x >> 1;
    const int row0 = by * BM, col0 = bx * 128;
    const int tid = threadIdx.x;
    const int lane = tid & 63, wid = tid >> 6;
    const int wr = wid >> 1, wc = wid & 1;
    const int lm = lane & 15, lk = lane >> 4;

    f32x4 acc[4][4] = {};

    for (int k0 = 0; k0 < K; k0 += BK) {
        // ---- stage A tile (128 rows x 64 k)
        if (A_IS_F32) {
            const float* A = (const float*)Av;
            #pragma unroll
            for (int i = 0; i < 8; i++) {
                int lin = tid + i * 256;           // 0..2047
                int r = lin >> 4, c4 = lin & 15;   // 16 float4 per row
                int gr = row0 + r;
                float4 v = make_float4(0.f, 0.f, 0.f, 0.f);
                if (gr < M) v = *(const float4*)(A + (size_t)gr * K + k0 + c4 * 4);
                uint2 p;
                p.x = (unsigned)f2bf(v.x) | ((unsigned)f2bf(v.y) << 16);
                p.y = (unsigned)f2bf(v.z) | ((unsigned)f2bf(v.w) << 16);
                *(uint2*)((char*)As + r * 128 + ((c4 * 8) ^ ((r & 7) << 4))) = p;
            }
        } else {
            const unsigned short* A = (const unsigned short*)Av;
            #pragma unroll
            for (int i = 0; i < 4; i++) {
                int lin = tid + i * 256;           // 0..1023
                int r = lin >> 3, c8 = lin & 7;    // 8 16B-chunks per row
                int gr = row0 + r;
                u16x8 v = {};
                if (gr < M) v = *(const u16x8*)(A + (size_t)gr * K + k0 + c8 * 8);
                *(u16x8*)((char*)As + r * 128 + ((c8 * 16) ^ ((r & 7) << 4))) = v;
            }
        }
        // ---- stage B tile (128 n-rows x 64 k) from Bt[N][K]
        #pragma unroll
        for (int i = 0; i < 4; i++) {
            int lin = tid + i * 256;
            int r = lin >> 3, c8 = lin & 7;
            u16x8 v = *(const u16x8*)(Bt + (size_t)(col0 + r) * K + k0 + c8 * 8);
            *(u16x8*)((char*)Bs + r * 128 + ((c8 * 16) ^ ((r & 7) << 4))) = v;
        }
        __syncthreads();

        #pragma unroll
        for (int kk = 0; kk < 2; kk++) {
            bf16x8 a[4], b[4];
            #pragma unroll
            for (int i = 0; i < 4; i++) {
                int m = wr * 64 + i * 16 + lm;
                a[i] = *(const bf16x8*)((const char*)As + m * 128 +
                        ((kk * 64 + lk * 16) ^ ((m & 7) << 4)));
            }
            #pragma unroll
            for (int j = 0; j < 4; j++) {
                int n = wc * 64 + j * 16 + lm;
                b[j] = *(const bf16x8*)((const char*)Bs + n * 128 +
                        ((kk * 64 + lk * 16) ^ ((n & 7) << 4)));
            }
            #pragma unroll
            for (int i = 0; i < 4; i++)
                #pragma unroll
                for (int j = 0; j < 4; j++)
                    acc[i][j] = __builtin_amdgcn_mfma_f32_16x16x32_bf16(
                        a[i], b[j], acc[i][j], 0, 0, 0);
        }
        __syncthreads();
    }

    // ---- epilogue.  D: col = lane&15, row = 4*(lane>>4)+q
    #pragma unroll
    for (int j = 0; j < 4; j++) {
        int gc = col0 + wc * 64 + j * 16 + lm;
        float bv = RELU_BIAS ? bias[gc] : 0.f;
        #pragma unroll
        for (int i = 0; i < 4; i++) {
            int gr0 = row0 + wr * 64 + i * 16 + lk * 4;
            #pragma unroll
            for (int q = 0; q < 4; q++) {
                int gr = gr0 + q;
                if (gr >= M) continue;
                float v = acc[i][j][q];
                if (RELU_BIAS) {
                    v += bv; v = v > 0.f ? v : 0.f;
                    ((float*)Cv)[(size_t)gr * 256 + gc] = v;
                } else {
                    ((unsigned short*)Cv)[(size_t)gr * 256 + gc] = f2bf(v);
                }
            }
        }
    }
}

// ------------------------------------------------------------------ scores
// one wave per node; lane owns 4 cols.  s = dot(Wh[n,h,:], a_src/dst[h,:])
__global__ __launch_bounds__(256) void scores_kernel(
    const unsigned short* __restrict__ Wh, const float* __restrict__ attn_fc,
    float* __restrict__ s_src, float* __restrict__ s_dst)
{
    const int lane = threadIdx.x & 63, wid = threadIdx.x >> 6;
    const int n = blockIdx.x * 4 + wid;
    const int h = lane >> 4;
    const int d0 = 4 * (lane & 15);            // col within head
    u16x4 w = *(const u16x4*)(Wh + (size_t)n * HID + 4 * lane);
    float ps = 0.f, pd = 0.f;
    #pragma unroll
    for (int q = 0; q < 4; q++) {
        float wf = bf2f(w[q]);
        ps += wf * attn_fc[h * 128 + d0 + q];
        pd += wf * attn_fc[h * 128 + 64 + d0 + q];
    }
    #pragma unroll
    for (int off = 8; off; off >>= 1) {
        ps += __shfl_xor(ps, off, 16);
        pd += __shfl_xor(pd, off, 16);
    }
    if ((lane & 15) == 0) {
        s_src[n * HEADS + h] = ps;
        s_dst[n * HEADS + h] = pd;
    }
}

// ------------------------------------------------------------------ edge pass: hist + global max
__global__ __launch_bounds__(256) void edge_pass_kernel(
    const int* __restrict__ erow, const int* __restrict__ ecol,
    const float* __restrict__ s_src, const float* __restrict__ s_dst,
    int* __restrict__ counts, float* __restrict__ gmax)
{
    float m[HEADS] = {-3.4e38f, -3.4e38f, -3.4e38f, -3.4e38f};
    for (int e = blockIdx.x * blockDim.x + threadIdx.x; e < E_EDGES;
         e += gridDim.x * blockDim.x) {
        int r = erow[e], c = ecol[e];
        atomicAdd(&counts[r], 1);
        float4 ss = ((const float4*)s_src)[r];
        float4 sd = ((const float4*)s_dst)[c];
        float sc[HEADS] = {ss.x + sd.x, ss.y + sd.y, ss.z + sd.z, ss.w + sd.w};
        #pragma unroll
        for (int h = 0; h < HEADS; h++) {
            float v = sc[h] > 0.f ? sc[h] : ALPHA * sc[h];
            m[h] = fmaxf(m[h], v);
        }
    }
    #pragma unroll
    for (int h = 0; h < HEADS; h++)
        #pragma unroll
        for (int off = 32; off; off >>= 1)
            m[h] = fmaxf(m[h], __shfl_xor(m[h], off, 64));
    if ((threadIdx.x & 63) == 0) {
        #pragma unroll
        for (int h = 0; h < HEADS; h++) atomicMaxFloat(&gmax[h], m[h]);
    }
}

// ------------------------------------------------------------------ 3-pass scan
// pass A: per-block (chunk=512) sums
__global__ __launch_bounds__(256) void scanA_kernel(
    const int* __restrict__ counts, int* __restrict__ bsum)
{
    const int b = blockIdx.x, tid = threadIdx.x;
    int i0 = b * 512 + tid;
    int v = 0;
    if (i0 < N_NODES) v += counts[i0];
    if (i0 + 256 < N_NODES) v += counts[i0 + 256];
    #pragma unroll
    for (int off = 32; off; off >>= 1) v += __shfl_xor(v, off, 64);
    __shared__ int ws[4];
    if ((tid & 63) == 0) ws[tid >> 6] = v;
    __syncthreads();
    if (tid == 0) bsum[b] = ws[0] + ws[1] + ws[2] + ws[3];
}

// pass B: exclusive scan of 98 block sums (1 block, 128 thr)
__global__ __launch_bounds__(128) void scanB_kernel(
    const int* __restrict__ bsum, int* __restrict__ bscan, int nb)
{
    const int tid = threadIdx.x;
    const int lane = tid & 63, wid = tid >> 6;
    int val = (tid < nb) ? bsum[tid] : 0;
    int x = val;
    #pragma unroll
    for (int off = 1; off < 64; off <<= 1) {
        int y = __shfl_up(x, off, 64);
        if (lane >= off) x += y;
    }
    __shared__ int w0;
    if (tid == 63) w0 = x;
    __syncthreads();
    if (wid == 1) x += w0;
    if (tid < nb) bscan[tid] = x - val;
}

// pass C: per-chunk local scan + offset; writes offsets & cursor
__global__ __launch_bounds__(512) void scanC_kernel(
    const int* __restrict__ counts, const int* __restrict__ bscan,
    int* __restrict__ offsets, int* __restrict__ cursor)
{
    const int b = blockIdx.x, tid = threadIdx.x;
    const int lane = tid & 63, wid = tid >> 6;
    const int i = b * 512 + tid;
    int v = (i < N_NODES) ? counts[i] : 0;
    int x = v;
    #pragma unroll
    for (int off = 1; off < 64; off <<= 1) {
        int y = __shfl_up(x, off, 64);
        if (lane >= off) x += y;
    }
    __shared__ int ws[8];
    if (lane == 63) ws[wid] = x;
    __syncthreads();
    if (wid == 0 && lane < 8) {
        int s = ws[lane];
        #pragma unroll
        for (int off = 1; off < 8; off <<= 1) {
            int y = __shfl_up(s, off, 8);
            if ((lane & 7) >= off) s += y;
        }
        ws[lane] = s;
    }
    __syncthreads();
    int prefix = (wid ? ws[wid - 1] : 0) + bscan[b];
    int excl = prefix + x - v;
    if (i < N_NODES) { offsets[i] = excl; cursor[i] = excl; }
    if (i == N_NODES - 1) offsets[N_NODES] = excl + v;
}

// ------------------------------------------------------------------ scatter
__global__ void scatter_kernel(const int* __restrict__ erow, const int* __restrict__ ecol,
                               int* __restrict__ cursor, int* __restrict__ sorted_col) {
    int e = blockIdx.x * blockDim.x + threadIdx.x;
    if (e >= E_EDGES) return;
    int r = erow[e];
    int pos = atomicAdd(&cursor[r], 1);
    sorted_col[pos] = ecol[e];
}

// ------------------------------------------------------------------ aggregate + residual + LN
// one wave per node; lane owns 4 cols (ushort4 bf16 loads); edge indices
// prefetched 64-wide and broadcast via shfl.
__global__ __launch_bounds__(256) void aggregate_ln_kernel(
    const unsigned short* __restrict__ Wh, const float* __restrict__ s_src,
    const float* __restrict__ s_dst, const float* __restrict__ gmax,
    const int* __restrict__ offsets, const int* __restrict__ sorted_col,
    const float* __restrict__ ln_gamma, const float* __restrict__ ln_beta,
    unsigned short* __restrict__ h_ln)
{
    const int lane = threadIdx.x & 63, wid = threadIdx.x >> 6;
    const int n = blockIdx.x * 4 + wid;
    const int h = lane >> 4;
    const int c0 = 4 * lane;
    const float ssrc = s_src[n * HEADS + h];
    const float gm = gmax[h];
    const int beg = offsets[n], end = offsets[n + 1];

    float acc[4] = {0.f, 0.f, 0.f, 0.f};
    float wsum = 0.f;
    for (int base = beg; base < end; base += 64) {
        int cnt = min(64, end - base);
        int cv = (base + lane < end) ? sorted_col[base + lane] : 0;
        for (int jj = 0; jj < cnt; jj++) {
            int c = __shfl(cv, jj, 64);
            float sd = s_dst[c * HEADS + h];
            float sc = ssrc + sd;
            sc = sc > 0.f ? sc : ALPHA * sc;
            float w = __expf(sc - gm);
            wsum += w;
            u16x4 wr = *(const u16x4*)(Wh + (size_t)c * HID + c0);
            #pragma unroll
            for (int q = 0; q < 4; q++) acc[q] += w * bf2f(wr[q]);
        }
    }
    u16x4 rr = *(const u16x4*)(Wh + (size_t)n * HID + c0);
    float inv_w = 1.f / (wsum + 1e-15f);
    float val[4];
    #pragma unroll
    for (int q = 0; q < 4; q++) val[q] = acc[q] * inv_w + bf2f(rr[q]);

    float s = val[0] + val[1] + val[2] + val[3];
    #pragma unroll
    for (int off = 32; off; off >>= 1) s += __shfl_xor(s, off, 64);
    float mu = s * (1.f / HID);
    float s2 = 0.f;
    #pragma unroll
    for (int q = 0; q < 4; q++) { float d = val[q] - mu; s2 += d * d; }
    #pragma unroll
    for (int off = 32; off; off >>= 1) s2 += __shfl_xor(s2, off, 64);
    float inv_std = rsqrtf(s2 * (1.f / HID) + LN_EPS);

    float4 g = *(const float4*)(ln_gamma + c0);
    float4 bb = *(const float4*)(ln_beta + c0);
    u16x4 outv;
    outv[0] = f2bf((val[0] - mu) * inv_std * g.x + bb.x);
    outv[1] = f2bf((val[1] - mu) * inv_std * g.y + bb.y);
    outv[2] = f2bf((val[2] - mu) * inv_std * g.z + bb.z);
    outv[3] = f2bf((val[3] - mu) * inv_std * g.w + bb.w);
    *(u16x4*)(h_ln + (size_t)n * HID + c0) = outv;
}

// ------------------------------------------------------------------ launch
extern "C" void kernel_launch(void* const* d_in, const int* in_sizes, int n_in,
                              void* d_out, int out_size, void* d_ws, size_t ws_size,
                              hipStream_t stream)
{
    const float* h        = (const float*)d_in[0];
    const int*   erow     = (const int*)  d_in[1];
    const int*   ecol     = (const int*)  d_in[2];
    const float* W        = (const float*)d_in[3];
    const float* attn_fc  = (const float*)d_in[4];
    const float* ln_gamma = (const float*)d_in[5];
    const float* ln_beta  = (const float*)d_in[6];
    const float* ffn_w    = (const float*)d_in[7];
    const float* ffn_b    = (const float*)d_in[8];
    float* out = (float*)d_out;

    // workspace layout
    unsigned short* Wh   = (unsigned short*)d_ws;            // N*HID bf16
    unsigned short* h_ln = Wh + (size_t)N_NODES * HID;       // N*HID bf16
    unsigned short* Wt   = h_ln + (size_t)N_NODES * HID;     // 256*256 bf16
    unsigned short* Ft   = Wt + 65536;                       // 256*256 bf16
    float* s_src  = (float*)(Ft + 65536);                    // N*HEADS
    float* s_dst  = s_src + N_NODES * HEADS;                 // N*HEADS
    float* gmax   = s_dst + N_NODES * HEADS;                 // 64
    int*   counts = (int*)(gmax + 64);                       // N
    int*   offsets = counts + N_NODES;                       // N+1
    int*   cursor  = offsets + N_NODES + 1;                  // N
    int*   sorted_col = cursor + N_NODES;                    // E
    int*   bsum   = sorted_col + E_EDGES;                    // 128
    int*   bscan  = bsum + 128;                              // 128

    const int NB = (N_NODES + 511) / 512;                    // 98

    hipMemsetAsync(counts, 0, N_NODES * sizeof(int), stream);
    prep_kernel<<<512, 256, 0, stream>>>(W, ffn_w, Wt, Ft, gmax);

    // Wh(bf16) = h(f32) @ W
    gemm_mfma<true, false><<<((N_NODES + 127) / 128) * 2, 256, 0, stream>>>(
        h, Wt, nullptr, Wh, N_NODES);

    scores_kernel<<<N_NODES / 4, 256, 0, stream>>>(Wh, attn_fc, s_src, s_dst);
    edge_pass_kernel<<<512, 256, 0, stream>>>(erow, ecol, s_src, s_dst, counts, gmax);
    scanA_kernel<<<NB, 256, 0, stream>>>(counts, bsum);
    scanB_kernel<<<1, 128, 0, stream>>>(bsum, bscan, NB);
    scanC_kernel<<<NB, 512, 0, stream>>>(counts, bscan, offsets, cursor);
    scatter_kernel<<<(E_EDGES + 255) / 256, 256, 0, stream>>>(erow, ecol, cursor, sorted_col);
    aggregate_ln_kernel<<<N_NODES / 4, 256, 0, stream>>>(
        Wh, s_src, s_dst, gmax, offsets, sorted_col, ln_gamma, ln_beta, h_ln);

    // out(f32) = relu(h_ln(bf16) @ ffn_w + b)
    gemm_mfma<false, true><<<((N_NODES + 127) / 128) * 2, 256, 0, stream>>>(
        h_ln, Ft, ffn_b, out, N_NODES);
}

// Round 3
// 281.569 us; speedup vs baseline: 2.3405x; 1.3297x over previous
//
#include <hip/hip_runtime.h>
#include <hip/hip_bf16.h>

#define N_NODES 50000
#define E_EDGES 400000
#define IN_CH   256
#define HEADS   4
#define OUT_CH  64
#define HID     256
#define ALPHA   0.2f
#define LN_EPS  1e-5f

using f32x4  = __attribute__((ext_vector_type(4))) float;
using bf16x8 = __attribute__((ext_vector_type(8))) short;   // 8 bf16 (4 VGPRs)
using u16x8  = __attribute__((ext_vector_type(8))) unsigned short;
using u16x4  = __attribute__((ext_vector_type(4))) unsigned short;

__device__ __forceinline__ unsigned short f2bf(float f) {
    __hip_bfloat16 b = __float2bfloat16(f);
    return *(unsigned short*)&b;
}
__device__ __forceinline__ float bf2f(unsigned short u) {
    __hip_bfloat16 b = *(__hip_bfloat16*)&u;
    return __bfloat162float(b);
}

// ------------------------------------------------------------------ prep
// Wt[n][k] = bf16(W[k][n]); Ft[n][k] = bf16(ffn_w[k][n])
__global__ __launch_bounds__(256) void prep_kernel(
    const float* __restrict__ W, const float* __restrict__ ffn_w,
    unsigned short* __restrict__ Wt, unsigned short* __restrict__ Ft)
{
    int i = blockIdx.x * 256 + threadIdx.x;
    if (i < 65536) {
        int n = i >> 8, k = i & 255;
        Wt[i] = f2bf(W[k * 256 + n]);
    } else {
        int j = i - 65536;
        int n = j >> 8, k = j & 255;
        Ft[j] = f2bf(ffn_w[k * 256 + n]);
    }
}

// ------------------------------------------------------------------ MFMA GEMM
// C[M,256] = A[M,256] @ B[256,256], B given pre-transposed bf16 Bt[N][K].
// BM=128, BN=128, BK=64; 256 thr = 4 waves (2x2), wave-tile 64x64.
template<bool A_IS_F32, bool RELU_BIAS>
__global__ __launch_bounds__(256) void gemm_mfma(
    const void* __restrict__ Av, const unsigned short* __restrict__ Bt,
    const float* __restrict__ bias, void* __restrict__ Cv, int M)
{
    constexpr int K = 256, BM = 128, BK = 64;
    __shared__ unsigned short As[BM * BK];   // row-major [128][64], XOR-swizzled
    __shared__ unsigned short Bs[BM * BK];

    const int bx = blockIdx.x & 1;           // N/BN = 2
    const int by = blockIdx.x >> 1;
    const int row0 = by * BM, col0 = bx * 128;
    const int tid = threadIdx.x;
    const int lane = tid & 63, wid = tid >> 6;
    const int wr = wid >> 1, wc = wid & 1;
    const int lm = lane & 15, lk = lane >> 4;

    f32x4 acc[4][4] = {};

    for (int k0 = 0; k0 < K; k0 += BK) {
        if (A_IS_F32) {
            const float* A = (const float*)Av;
            #pragma unroll
            for (int i = 0; i < 8; i++) {
                int lin = tid + i * 256;           // 0..2047
                int r = lin >> 4, c4 = lin & 15;   // 16 float4 per row
                int gr = row0 + r;
                float4 v = make_float4(0.f, 0.f, 0.f, 0.f);
                if (gr < M) v = *(const float4*)(A + (size_t)gr * K + k0 + c4 * 4);
                uint2 p;
                p.x = (unsigned)f2bf(v.x) | ((unsigned)f2bf(v.y) << 16);
                p.y = (unsigned)f2bf(v.z) | ((unsigned)f2bf(v.w) << 16);
                *(uint2*)((char*)As + r * 128 + ((c4 * 8) ^ ((r & 7) << 4))) = p;
            }
        } else {
            const unsigned short* A = (const unsigned short*)Av;
            #pragma unroll
            for (int i = 0; i < 4; i++) {
                int lin = tid + i * 256;           // 0..1023
                int r = lin >> 3, c8 = lin & 7;    // 8 16B-chunks per row
                int gr = row0 + r;
                u16x8 v = {};
                if (gr < M) v = *(const u16x8*)(A + (size_t)gr * K + k0 + c8 * 8);
                *(u16x8*)((char*)As + r * 128 + ((c8 * 16) ^ ((r & 7) << 4))) = v;
            }
        }
        #pragma unroll
        for (int i = 0; i < 4; i++) {
            int lin = tid + i * 256;
            int r = lin >> 3, c8 = lin & 7;
            u16x8 v = *(const u16x8*)(Bt + (size_t)(col0 + r) * K + k0 + c8 * 8);
            *(u16x8*)((char*)Bs + r * 128 + ((c8 * 16) ^ ((r & 7) << 4))) = v;
        }
        __syncthreads();

        #pragma unroll
        for (int kk = 0; kk < 2; kk++) {
            bf16x8 a[4], b[4];
            #pragma unroll
            for (int i = 0; i < 4; i++) {
                int m = wr * 64 + i * 16 + lm;
                a[i] = *(const bf16x8*)((const char*)As + m * 128 +
                        ((kk * 64 + lk * 16) ^ ((m & 7) << 4)));
            }
            #pragma unroll
            for (int j = 0; j < 4; j++) {
                int n = wc * 64 + j * 16 + lm;
                b[j] = *(const bf16x8*)((const char*)Bs + n * 128 +
                        ((kk * 64 + lk * 16) ^ ((n & 7) << 4)));
            }
            #pragma unroll
            for (int i = 0; i < 4; i++)
                #pragma unroll
                for (int j = 0; j < 4; j++)
                    acc[i][j] = __builtin_amdgcn_mfma_f32_16x16x32_bf16(
                        a[i], b[j], acc[i][j], 0, 0, 0);
        }
        __syncthreads();
    }

    // ---- epilogue.  D: col = lane&15, row = 4*(lane>>4)+q
    #pragma unroll
    for (int j = 0; j < 4; j++) {
        int gc = col0 + wc * 64 + j * 16 + lm;
        float bv = RELU_BIAS ? bias[gc] : 0.f;
        #pragma unroll
        for (int i = 0; i < 4; i++) {
            int gr0 = row0 + wr * 64 + i * 16 + lk * 4;
            #pragma unroll
            for (int q = 0; q < 4; q++) {
                int gr = gr0 + q;
                if (gr >= M) continue;
                float v = acc[i][j][q];
                if (RELU_BIAS) {
                    v += bv; v = v > 0.f ? v : 0.f;
                    ((float*)Cv)[(size_t)gr * 256 + gc] = v;
                } else {
                    ((unsigned short*)Cv)[(size_t)gr * 256 + gc] = f2bf(v);
                }
            }
        }
    }
}

// ------------------------------------------------------------------ scores
__global__ __launch_bounds__(256) void scores_kernel(
    const unsigned short* __restrict__ Wh, const float* __restrict__ attn_fc,
    float* __restrict__ s_src, float* __restrict__ s_dst)
{
    const int lane = threadIdx.x & 63, wid = threadIdx.x >> 6;
    const int n = blockIdx.x * 4 + wid;
    const int h = lane >> 4;
    const int d0 = 4 * (lane & 15);
    u16x4 w = *(const u16x4*)(Wh + (size_t)n * HID + 4 * lane);
    float ps = 0.f, pd = 0.f;
    #pragma unroll
    for (int q = 0; q < 4; q++) {
        float wf = bf2f(w[q]);
        ps += wf * attn_fc[h * 128 + d0 + q];
        pd += wf * attn_fc[h * 128 + 64 + d0 + q];
    }
    #pragma unroll
    for (int off = 8; off; off >>= 1) {
        ps += __shfl_xor(ps, off, 16);
        pd += __shfl_xor(pd, off, 16);
    }
    if ((lane & 15) == 0) {
        s_src[n * HEADS + h] = ps;
        s_dst[n * HEADS + h] = pd;
    }
}

// ------------------------------------------------------------------ histogram
__global__ void hist_kernel(const int* __restrict__ erow, int* __restrict__ counts) {
    int e = blockIdx.x * blockDim.x + threadIdx.x;
    if (e < E_EDGES) atomicAdd(&counts[erow[e]], 1);
}

// ------------------------------------------------------------------ 3-pass scan
__global__ __launch_bounds__(256) void scanA_kernel(
    const int* __restrict__ counts, int* __restrict__ bsum)
{
    const int b = blockIdx.x, tid = threadIdx.x;
    int i0 = b * 512 + tid;
    int v = 0;
    if (i0 < N_NODES) v += counts[i0];
    if (i0 + 256 < N_NODES) v += counts[i0 + 256];
    #pragma unroll
    for (int off = 32; off; off >>= 1) v += __shfl_xor(v, off, 64);
    __shared__ int ws[4];
    if ((tid & 63) == 0) ws[tid >> 6] = v;
    __syncthreads();
    if (tid == 0) bsum[b] = ws[0] + ws[1] + ws[2] + ws[3];
}

__global__ __launch_bounds__(128) void scanB_kernel(
    const int* __restrict__ bsum, int* __restrict__ bscan, int nb)
{
    const int tid = threadIdx.x;
    const int lane = tid & 63, wid = tid >> 6;
    int val = (tid < nb) ? bsum[tid] : 0;
    int x = val;
    #pragma unroll
    for (int off = 1; off < 64; off <<= 1) {
        int y = __shfl_up(x, off, 64);
        if (lane >= off) x += y;
    }
    __shared__ int w0;
    if (tid == 63) w0 = x;
    __syncthreads();
    if (wid == 1) x += w0;
    if (tid < nb) bscan[tid] = x - val;
}

__global__ __launch_bounds__(512) void scanC_kernel(
    const int* __restrict__ counts, const int* __restrict__ bscan,
    int* __restrict__ offsets, int* __restrict__ cursor)
{
    const int b = blockIdx.x, tid = threadIdx.x;
    const int lane = tid & 63, wid = tid >> 6;
    const int i = b * 512 + tid;
    int v = (i < N_NODES) ? counts[i] : 0;
    int x = v;
    #pragma unroll
    for (int off = 1; off < 64; off <<= 1) {
        int y = __shfl_up(x, off, 64);
        if (lane >= off) x += y;
    }
    __shared__ int ws[8];
    if (lane == 63) ws[wid] = x;
    __syncthreads();
    if (wid == 0 && lane < 8) {
        int s = ws[lane];
        #pragma unroll
        for (int off = 1; off < 8; off <<= 1) {
            int y = __shfl_up(s, off, 8);
            if ((lane & 7) >= off) s += y;
        }
        ws[lane] = s;
    }
    __syncthreads();
    int prefix = (wid ? ws[wid - 1] : 0) + bscan[b];
    int excl = prefix + x - v;
    if (i < N_NODES) { offsets[i] = excl; cursor[i] = excl; }
    if (i == N_NODES - 1) offsets[N_NODES] = excl + v;
}

// ------------------------------------------------------------------ scatter + weight precompute
// w[e,h] = exp(leaky(s_src[row]+s_dst[col]))  (global-max term cancels in alpha)
__global__ __launch_bounds__(256) void scatter_kernel(
    const int* __restrict__ erow, const int* __restrict__ ecol,
    const float* __restrict__ s_src, const float* __restrict__ s_dst,
    int* __restrict__ cursor, int* __restrict__ sorted_col,
    float4* __restrict__ sorted_w)
{
    int e = blockIdx.x * blockDim.x + threadIdx.x;
    if (e >= E_EDGES) return;
    int r = erow[e], c = ecol[e];
    float4 ss = ((const float4*)s_src)[r];
    float4 sd = ((const float4*)s_dst)[c];
    float sc[4] = {ss.x + sd.x, ss.y + sd.y, ss.z + sd.z, ss.w + sd.w};
    float4 w;
    float* wp = (float*)&w;
    #pragma unroll
    for (int h = 0; h < 4; h++) {
        float v = sc[h] > 0.f ? sc[h] : ALPHA * sc[h];
        wp[h] = __expf(v);
    }
    int pos = atomicAdd(&cursor[r], 1);
    sorted_col[pos] = c;
    sorted_w[pos] = w;
}

// ------------------------------------------------------------------ aggregate + residual + LN
// one wave per node; lane owns 4 cols; weights precomputed (independent loads).
__global__ __launch_bounds__(256) void aggregate_ln_kernel(
    const unsigned short* __restrict__ Wh, const float* __restrict__ sorted_w,
    const int* __restrict__ offsets, const int* __restrict__ sorted_col,
    const float* __restrict__ ln_gamma, const float* __restrict__ ln_beta,
    unsigned short* __restrict__ h_ln)
{
    const int lane = threadIdx.x & 63, wid = threadIdx.x >> 6;
    const int n = blockIdx.x * 4 + wid;
    const int h = lane >> 4;
    const int c0 = 4 * lane;
    const int beg = offsets[n], end = offsets[n + 1];

    float acc[4] = {0.f, 0.f, 0.f, 0.f};
    float wsum = 0.f;
    for (int base = beg; base < end; base += 64) {
        int cnt = min(64, end - base);
        int cv = (base + lane < end) ? sorted_col[base + lane] : 0;
        #pragma unroll 2
        for (int jj = 0; jj < cnt; jj++) {
            float w = sorted_w[(base + jj) * 4 + h];   // broadcast in 16-lane group
            int c = __shfl(cv, jj, 64);
            u16x4 wr = *(const u16x4*)(Wh + (size_t)c * HID + c0);
            wsum += w;
            #pragma unroll
            for (int q = 0; q < 4; q++) acc[q] += w * bf2f(wr[q]);
        }
    }
    u16x4 rr = *(const u16x4*)(Wh + (size_t)n * HID + c0);
    float inv_w = 1.f / (wsum + 1e-15f);
    float val[4];
    #pragma unroll
    for (int q = 0; q < 4; q++) val[q] = acc[q] * inv_w + bf2f(rr[q]);

    float s = val[0] + val[1] + val[2] + val[3];
    #pragma unroll
    for (int off = 32; off; off >>= 1) s += __shfl_xor(s, off, 64);
    float mu = s * (1.f / HID);
    float s2 = 0.f;
    #pragma unroll
    for (int q = 0; q < 4; q++) { float d = val[q] - mu; s2 += d * d; }
    #pragma unroll
    for (int off = 32; off; off >>= 1) s2 += __shfl_xor(s2, off, 64);
    float inv_std = rsqrtf(s2 * (1.f / HID) + LN_EPS);

    float4 g = *(const float4*)(ln_gamma + c0);
    float4 bb = *(const float4*)(ln_beta + c0);
    u16x4 outv;
    outv[0] = f2bf((val[0] - mu) * inv_std * g.x + bb.x);
    outv[1] = f2bf((val[1] - mu) * inv_std * g.y + bb.y);
    outv[2] = f2bf((val[2] - mu) * inv_std * g.z + bb.z);
    outv[3] = f2bf((val[3] - mu) * inv_std * g.w + bb.w);
    *(u16x4*)(h_ln + (size_t)n * HID + c0) = outv;
}

// ------------------------------------------------------------------ launch
extern "C" void kernel_launch(void* const* d_in, const int* in_sizes, int n_in,
                              void* d_out, int out_size, void* d_ws, size_t ws_size,
                              hipStream_t stream)
{
    const float* h        = (const float*)d_in[0];
    const int*   erow     = (const int*)  d_in[1];
    const int*   ecol     = (const int*)  d_in[2];
    const float* W        = (const float*)d_in[3];
    const float* attn_fc  = (const float*)d_in[4];
    const float* ln_gamma = (const float*)d_in[5];
    const float* ln_beta  = (const float*)d_in[6];
    const float* ffn_w    = (const float*)d_in[7];
    const float* ffn_b    = (const float*)d_in[8];
    float* out = (float*)d_out;

    // workspace layout (16B-aligned float4 arrays)
    unsigned short* Wh   = (unsigned short*)d_ws;            // N*HID bf16
    unsigned short* h_ln = Wh + (size_t)N_NODES * HID;       // N*HID bf16
    unsigned short* Wt   = h_ln + (size_t)N_NODES * HID;     // 256*256 bf16
    unsigned short* Ft   = Wt + 65536;                       // 256*256 bf16
    float* s_src  = (float*)(Ft + 65536);                    // N*HEADS
    float* s_dst  = s_src + N_NODES * HEADS;                 // N*HEADS
    float* sorted_w = s_dst + N_NODES * HEADS;               // E*HEADS
    int*   counts = (int*)(sorted_w + (size_t)E_EDGES * HEADS); // N
    int*   offsets = counts + N_NODES;                       // N+1
    int*   cursor  = offsets + N_NODES + 1;                  // N
    int*   sorted_col = cursor + N_NODES;                    // E
    int*   bsum   = sorted_col + E_EDGES;                    // 128
    int*   bscan  = bsum + 128;                              // 128

    const int NB = (N_NODES + 511) / 512;                    // 98

    hipMemsetAsync(counts, 0, N_NODES * sizeof(int), stream);
    prep_kernel<<<512, 256, 0, stream>>>(W, ffn_w, Wt, Ft);

    // Wh(bf16) = h(f32) @ W
    gemm_mfma<true, false><<<((N_NODES + 127) / 128) * 2, 256, 0, stream>>>(
        h, Wt, nullptr, Wh, N_NODES);

    scores_kernel<<<N_NODES / 4, 256, 0, stream>>>(Wh, attn_fc, s_src, s_dst);
    hist_kernel<<<(E_EDGES + 255) / 256, 256, 0, stream>>>(erow, counts);
    scanA_kernel<<<NB, 256, 0, stream>>>(counts, bsum);
    scanB_kernel<<<1, 128, 0, stream>>>(bsum, bscan, NB);
    scanC_kernel<<<NB, 512, 0, stream>>>(counts, bscan, offsets, cursor);
    scatter_kernel<<<(E_EDGES + 255) / 256, 256, 0, stream>>>(
        erow, ecol, s_src, s_dst, cursor, sorted_col, (float4*)sorted_w);
    aggregate_ln_kernel<<<N_NODES / 4, 256, 0, stream>>>(
        Wh, sorted_w, offsets, sorted_col, ln_gamma, ln_beta, h_ln);

    // out(f32) = relu(h_ln(bf16) @ ffn_w + b)
    gemm_mfma<false, true><<<((N_NODES + 127) / 128) * 2, 256, 0, stream>>>(
        h_ln, Ft, ffn_b, out, N_NODES);
}

// Round 4
// 276.463 us; speedup vs baseline: 2.3837x; 1.0185x over previous
//
#include <hip/hip_runtime.h>
#include <hip/hip_bf16.h>

#define N_NODES 50000
#define E_EDGES 400000
#define IN_CH   256
#define HEADS   4
#define OUT_CH  64
#define HID     256
#define ALPHA   0.2f
#define LN_EPS  1e-5f

using f32x4  = __attribute__((ext_vector_type(4))) float;
using bf16x8 = __attribute__((ext_vector_type(8))) short;   // 8 bf16 (4 VGPRs)
using u16x8  = __attribute__((ext_vector_type(8))) unsigned short;
using u16x4  = __attribute__((ext_vector_type(4))) unsigned short;

typedef __attribute__((address_space(3))) void* lds_vp;
typedef const __attribute__((address_space(1))) void* gbl_vp;

__device__ __forceinline__ unsigned short f2bf(float f) {
    __hip_bfloat16 b = __float2bfloat16(f);
    return *(unsigned short*)&b;
}
__device__ __forceinline__ float bf2f(unsigned short u) {
    __hip_bfloat16 b = *(__hip_bfloat16*)&u;
    return __bfloat162float(b);
}

// ------------------------------------------------------------------ prep
// Wt[n][k] = bf16(W[k][n]); Ft[n][k] = bf16(ffn_w[k][n])
__global__ __launch_bounds__(256) void prep_kernel(
    const float* __restrict__ W, const float* __restrict__ ffn_w,
    unsigned short* __restrict__ Wt, unsigned short* __restrict__ Ft)
{
    int i = blockIdx.x * 256 + threadIdx.x;
    if (i < 65536) {
        int n = i >> 8, k = i & 255;
        Wt[i] = f2bf(W[k * 256 + n]);
    } else {
        int j = i - 65536;
        int n = j >> 8, k = j & 255;
        Ft[j] = f2bf(ffn_w[k * 256 + n]);
    }
}

// ------------------------------------------------------------------ MFMA GEMM (double-buffered)
// C[M,256] = A[M,256] @ B[256,256], B pre-transposed bf16 Bt[N][K].
// BM=128, BN=128, BK=64; 256 thr = 4 waves (2x2), wave-tile 64x64.
// LDS layout: [128 rows][64 k] bf16, 16B-chunk XOR-swizzle: chunk c at row r
// holds global chunk c ^ (r&7).  global_load_lds writes LINEAR dest; the
// inverse swizzle is applied to the per-lane GLOBAL source address.
template<bool A_IS_F32, bool RELU_BIAS, bool SCORES>
__global__ __launch_bounds__(256) void gemm_mfma(
    const void* __restrict__ Av, const unsigned short* __restrict__ Bt,
    const float* __restrict__ bias, const float* __restrict__ attn_fc,
    void* __restrict__ Cv, float* __restrict__ s_src, float* __restrict__ s_dst,
    int M)
{
    constexpr int K = 256, BK = 64, NT = K / BK;   // 4 K-steps
    __shared__ unsigned short As[2][128 * 64];
    __shared__ unsigned short Bs[2][128 * 64];

    const int bx = blockIdx.x & 1;           // N/BN = 2
    const int by = blockIdx.x >> 1;
    const int row0 = by * 128, col0 = bx * 128;
    const int tid = threadIdx.x;
    const int lane = tid & 63, wid = tid >> 6;
    const int wr = wid >> 1, wc = wid & 1;
    const int lm = lane & 15, lk = lane >> 4;

    f32x4 acc[4][4] = {};

    // ---- staging helpers --------------------------------------------------
    auto stageB = [&](int buf, int k0) {
        #pragma unroll
        for (int i = 0; i < 4; i++) {
            int lin = wid * 64 + lane + i * 256;      // 0..1023 chunk id
            int r = lin >> 3, c8 = lin & 7;
            int c8s = c8 ^ (r & 7);                   // inverse swizzle on source
            const unsigned short* g = Bt + (size_t)(col0 + r) * K + k0 + c8s * 8;
            __builtin_amdgcn_global_load_lds((gbl_vp)g,
                (lds_vp)&Bs[buf][(size_t)(i * 256 + wid * 64) * 8], 16, 0, 0);
        }
    };
    auto stageA_bf16 = [&](int buf, int k0) {
        const unsigned short* A = (const unsigned short*)Av;
        #pragma unroll
        for (int i = 0; i < 4; i++) {
            int lin = wid * 64 + lane + i * 256;
            int r = lin >> 3, c8 = lin & 7;
            int c8s = c8 ^ (r & 7);
            const unsigned short* g = A + (size_t)(row0 + r) * K + k0 + c8s * 8;
            // OOB rows (row0+r >= M) read workspace garbage; those acc rows
            // are never written back.
            __builtin_amdgcn_global_load_lds((gbl_vp)g,
                (lds_vp)&As[buf][(size_t)(i * 256 + wid * 64) * 8], 16, 0, 0);
        }
    };
    auto stageA_f32 = [&](int buf, int k0) {
        const float* A = (const float*)Av;
        #pragma unroll
        for (int i = 0; i < 8; i++) {
            int lin = tid + i * 256;                  // 0..2047
            int r = lin >> 4, c4 = lin & 15;          // 16 float4 per row
            int gr = row0 + r;
            float4 v = make_float4(0.f, 0.f, 0.f, 0.f);
            if (gr < M) v = *(const float4*)(A + (size_t)gr * K + k0 + c4 * 4);
            uint2 p;
            p.x = (unsigned)f2bf(v.x) | ((unsigned)f2bf(v.y) << 16);
            p.y = (unsigned)f2bf(v.z) | ((unsigned)f2bf(v.w) << 16);
            *(uint2*)((char*)&As[buf][0] + r * 128 + ((c4 * 8) ^ ((r & 7) << 4))) = p;
        }
    };
    auto stage = [&](int buf, int k0) {
        if (A_IS_F32) stageA_f32(buf, k0); else stageA_bf16(buf, k0);
        stageB(buf, k0);
    };
    auto compute = [&](int buf) {
        #pragma unroll
        for (int kk = 0; kk < 2; kk++) {
            bf16x8 a[4], b[4];
            #pragma unroll
            for (int i = 0; i < 4; i++) {
                int m = wr * 64 + i * 16 + lm;
                a[i] = *(const bf16x8*)((const char*)&As[buf][0] + m * 128 +
                        ((kk * 64 + lk * 16) ^ ((m & 7) << 4)));
            }
            #pragma unroll
            for (int j = 0; j < 4; j++) {
                int n = wc * 64 + j * 16 + lm;
                b[j] = *(const bf16x8*)((const char*)&Bs[buf][0] + n * 128 +
                        ((kk * 64 + lk * 16) ^ ((n & 7) << 4)));
            }
            #pragma unroll
            for (int i = 0; i < 4; i++)
                #pragma unroll
                for (int j = 0; j < 4; j++)
                    acc[i][j] = __builtin_amdgcn_mfma_f32_16x16x32_bf16(
                        a[i], b[j], acc[i][j], 0, 0, 0);
        }
    };

    // ---- pipeline: stage(t+1) issued before compute(t); 1 barrier / K-step
    stage(0, 0);
    __syncthreads();
    #pragma unroll
    for (int t = 0; t < NT; t++) {
        if (t + 1 < NT) stage((t + 1) & 1, (t + 1) * BK);
        compute(t & 1);
        __syncthreads();
    }

    // ---- epilogue.  D: col = lane&15 (lm), row = 4*(lane>>4)+q
    #pragma unroll
    for (int j = 0; j < 4; j++) {
        int gc = col0 + wc * 64 + j * 16 + lm;
        float bv = RELU_BIAS ? bias[gc] : 0.f;
        #pragma unroll
        for (int i = 0; i < 4; i++) {
            int gr0 = row0 + wr * 64 + i * 16 + lk * 4;
            #pragma unroll
            for (int q = 0; q < 4; q++) {
                int gr = gr0 + q;
                if (gr >= M) continue;
                float v = acc[i][j][q];
                if (RELU_BIAS) {
                    v += bv; v = v > 0.f ? v : 0.f;
                    ((float*)Cv)[(size_t)gr * 256 + gc] = v;
                } else {
                    ((unsigned short*)Cv)[(size_t)gr * 256 + gc] = f2bf(v);
                }
            }
        }
    }

    // ---- fused attention scores (GEMM1 only): wave's 64-col tile == 1 head
    if (SCORES) {
        const int head = bx * 2 + wc;
        float as[4], ad[4];
        #pragma unroll
        for (int j = 0; j < 4; j++) {
            as[j] = attn_fc[head * 128 + j * 16 + lm];
            ad[j] = attn_fc[head * 128 + 64 + j * 16 + lm];
        }
        #pragma unroll
        for (int i = 0; i < 4; i++) {
            #pragma unroll
            for (int q = 0; q < 4; q++) {
                float ps = 0.f, pd = 0.f;
                #pragma unroll
                for (int j = 0; j < 4; j++) {
                    ps += acc[i][j][q] * as[j];
                    pd += acc[i][j][q] * ad[j];
                }
                #pragma unroll
                for (int off = 8; off; off >>= 1) {
                    ps += __shfl_xor(ps, off, 16);
                    pd += __shfl_xor(pd, off, 16);
                }
                int gr = row0 + wr * 64 + i * 16 + lk * 4 + q;
                if (lm == 0 && gr < M) {
                    s_src[gr * HEADS + head] = ps;
                    s_dst[gr * HEADS + head] = pd;
                }
            }
        }
    }
}

// ------------------------------------------------------------------ histogram
__global__ void hist_kernel(const int* __restrict__ erow, int* __restrict__ counts) {
    int e = blockIdx.x * blockDim.x + threadIdx.x;
    if (e < E_EDGES) atomicAdd(&counts[erow[e]], 1);
}

// ------------------------------------------------------------------ 3-pass scan
__global__ __launch_bounds__(256) void scanA_kernel(
    const int* __restrict__ counts, int* __restrict__ bsum)
{
    const int b = blockIdx.x, tid = threadIdx.x;
    int i0 = b * 512 + tid;
    int v = 0;
    if (i0 < N_NODES) v += counts[i0];
    if (i0 + 256 < N_NODES) v += counts[i0 + 256];
    #pragma unroll
    for (int off = 32; off; off >>= 1) v += __shfl_xor(v, off, 64);
    __shared__ int ws[4];
    if ((tid & 63) == 0) ws[tid >> 6] = v;
    __syncthreads();
    if (tid == 0) bsum[b] = ws[0] + ws[1] + ws[2] + ws[3];
}

__global__ __launch_bounds__(128) void scanB_kernel(
    const int* __restrict__ bsum, int* __restrict__ bscan, int nb)
{
    const int tid = threadIdx.x;
    const int lane = tid & 63, wid = tid >> 6;
    int val = (tid < nb) ? bsum[tid] : 0;
    int x = val;
    #pragma unroll
    for (int off = 1; off < 64; off <<= 1) {
        int y = __shfl_up(x, off, 64);
        if (lane >= off) x += y;
    }
    __shared__ int w0;
    if (tid == 63) w0 = x;
    __syncthreads();
    if (wid == 1) x += w0;
    if (tid < nb) bscan[tid] = x - val;
}

__global__ __launch_bounds__(512) void scanC_kernel(
    const int* __restrict__ counts, const int* __restrict__ bscan,
    int* __restrict__ offsets, int* __restrict__ cursor)
{
    const int b = blockIdx.x, tid = threadIdx.x;
    const int lane = tid & 63, wid = tid >> 6;
    const int i = b * 512 + tid;
    int v = (i < N_NODES) ? counts[i] : 0;
    int x = v;
    #pragma unroll
    for (int off = 1; off < 64; off <<= 1) {
        int y = __shfl_up(x, off, 64);
        if (lane >= off) x += y;
    }
    __shared__ int ws[8];
    if (lane == 63) ws[wid] = x;
    __syncthreads();
    if (wid == 0 && lane < 8) {
        int s = ws[lane];
        #pragma unroll
        for (int off = 1; off < 8; off <<= 1) {
            int y = __shfl_up(s, off, 8);
            if ((lane & 7) >= off) s += y;
        }
        ws[lane] = s;
    }
    __syncthreads();
    int prefix = (wid ? ws[wid - 1] : 0) + bscan[b];
    int excl = prefix + x - v;
    if (i < N_NODES) { offsets[i] = excl; cursor[i] = excl; }
    if (i == N_NODES - 1) offsets[N_NODES] = excl + v;
}

// ------------------------------------------------------------------ scatter + weight precompute
// w[e,h] = exp(leaky(s_src[row]+s_dst[col]))  (global-max term cancels in alpha)
__global__ __launch_bounds__(256) void scatter_kernel(
    const int* __restrict__ erow, const int* __restrict__ ecol,
    const float* __restrict__ s_src, const float* __restrict__ s_dst,
    int* __restrict__ cursor, int* __restrict__ sorted_col,
    float4* __restrict__ sorted_w)
{
    int e = blockIdx.x * blockDim.x + threadIdx.x;
    if (e >= E_EDGES) return;
    int r = erow[e], c = ecol[e];
    float4 ss = ((const float4*)s_src)[r];
    float4 sd = ((const float4*)s_dst)[c];
    float sc[4] = {ss.x + sd.x, ss.y + sd.y, ss.z + sd.z, ss.w + sd.w};
    float4 w;
    float* wp = (float*)&w;
    #pragma unroll
    for (int h = 0; h < 4; h++) {
        float v = sc[h] > 0.f ? sc[h] : ALPHA * sc[h];
        wp[h] = __expf(v);
    }
    int pos = atomicAdd(&cursor[r], 1);
    sorted_col[pos] = c;
    sorted_w[pos] = w;
}

// ------------------------------------------------------------------ aggregate + residual + LN
__global__ __launch_bounds__(256) void aggregate_ln_kernel(
    const unsigned short* __restrict__ Wh, const float* __restrict__ sorted_w,
    const int* __restrict__ offsets, const int* __restrict__ sorted_col,
    const float* __restrict__ ln_gamma, const float* __restrict__ ln_beta,
    unsigned short* __restrict__ h_ln)
{
    const int lane = threadIdx.x & 63, wid = threadIdx.x >> 6;
    const int n = blockIdx.x * 4 + wid;
    const int h = lane >> 4;
    const int c0 = 4 * lane;
    const int beg = offsets[n], end = offsets[n + 1];

    float acc[4] = {0.f, 0.f, 0.f, 0.f};
    float wsum = 0.f;
    for (int base = beg; base < end; base += 64) {
        int cnt = min(64, end - base);
        int cv = (base + lane < end) ? sorted_col[base + lane] : 0;
        #pragma unroll 2
        for (int jj = 0; jj < cnt; jj++) {
            float w = sorted_w[(base + jj) * 4 + h];   // broadcast in 16-lane group
            int c = __shfl(cv, jj, 64);
            u16x4 wr = *(const u16x4*)(Wh + (size_t)c * HID + c0);
            wsum += w;
            #pragma unroll
            for (int q = 0; q < 4; q++) acc[q] += w * bf2f(wr[q]);
        }
    }
    u16x4 rr = *(const u16x4*)(Wh + (size_t)n * HID + c0);
    float inv_w = 1.f / (wsum + 1e-15f);
    float val[4];
    #pragma unroll
    for (int q = 0; q < 4; q++) val[q] = acc[q] * inv_w + bf2f(rr[q]);

    float s = val[0] + val[1] + val[2] + val[3];
    #pragma unroll
    for (int off = 32; off; off >>= 1) s += __shfl_xor(s, off, 64);
    float mu = s * (1.f / HID);
    float s2 = 0.f;
    #pragma unroll
    for (int q = 0; q < 4; q++) { float d = val[q] - mu; s2 += d * d; }
    #pragma unroll
    for (int off = 32; off; off >>= 1) s2 += __shfl_xor(s2, off, 64);
    float inv_std = rsqrtf(s2 * (1.f / HID) + LN_EPS);

    float4 g = *(const float4*)(ln_gamma + c0);
    float4 bb = *(const float4*)(ln_beta + c0);
    u16x4 outv;
    outv[0] = f2bf((val[0] - mu) * inv_std * g.x + bb.x);
    outv[1] = f2bf((val[1] - mu) * inv_std * g.y + bb.y);
    outv[2] = f2bf((val[2] - mu) * inv_std * g.z + bb.z);
    outv[3] = f2bf((val[3] - mu) * inv_std * g.w + bb.w);
    *(u16x4*)(h_ln + (size_t)n * HID + c0) = outv;
}

// ------------------------------------------------------------------ launch
extern "C" void kernel_launch(void* const* d_in, const int* in_sizes, int n_in,
                              void* d_out, int out_size, void* d_ws, size_t ws_size,
                              hipStream_t stream)
{
    const float* h        = (const float*)d_in[0];
    const int*   erow     = (const int*)  d_in[1];
    const int*   ecol     = (const int*)  d_in[2];
    const float* W        = (const float*)d_in[3];
    const float* attn_fc  = (const float*)d_in[4];
    const float* ln_gamma = (const float*)d_in[5];
    const float* ln_beta  = (const float*)d_in[6];
    const float* ffn_w    = (const float*)d_in[7];
    const float* ffn_b    = (const float*)d_in[8];
    float* out = (float*)d_out;

    // workspace layout (16B-aligned float4 arrays)
    unsigned short* Wh   = (unsigned short*)d_ws;            // N*HID bf16
    unsigned short* h_ln = Wh + (size_t)N_NODES * HID;       // N*HID bf16
    unsigned short* Wt   = h_ln + (size_t)N_NODES * HID;     // 256*256 bf16
    unsigned short* Ft   = Wt + 65536;                       // 256*256 bf16
    float* s_src  = (float*)(Ft + 65536);                    // N*HEADS
    float* s_dst  = s_src + N_NODES * HEADS;                 // N*HEADS
    float* sorted_w = s_dst + N_NODES * HEADS;               // E*HEADS
    int*   counts = (int*)(sorted_w + (size_t)E_EDGES * HEADS); // N
    int*   offsets = counts + N_NODES;                       // N+1
    int*   cursor  = offsets + N_NODES + 1;                  // N
    int*   sorted_col = cursor + N_NODES;                    // E
    int*   bsum   = sorted_col + E_EDGES;                    // 128
    int*   bscan  = bsum + 128;                              // 128

    const int NB = (N_NODES + 511) / 512;                    // 98

    hipMemsetAsync(counts, 0, N_NODES * sizeof(int), stream);
    prep_kernel<<<512, 256, 0, stream>>>(W, ffn_w, Wt, Ft);

    // Wh(bf16) = h(f32) @ W ; fused s_src/s_dst from f32 accumulators
    gemm_mfma<true, false, true><<<((N_NODES + 127) / 128) * 2, 256, 0, stream>>>(
        h, Wt, nullptr, attn_fc, Wh, s_src, s_dst, N_NODES);

    hist_kernel<<<(E_EDGES + 255) / 256, 256, 0, stream>>>(erow, counts);
    scanA_kernel<<<NB, 256, 0, stream>>>(counts, bsum);
    scanB_kernel<<<1, 128, 0, stream>>>(bsum, bscan, NB);
    scanC_kernel<<<NB, 512, 0, stream>>>(counts, bscan, offsets, cursor);
    scatter_kernel<<<(E_EDGES + 255) / 256, 256, 0, stream>>>(
        erow, ecol, s_src, s_dst, cursor, sorted_col, (float4*)sorted_w);
    aggregate_ln_kernel<<<N_NODES / 4, 256, 0, stream>>>(
        Wh, sorted_w, offsets, sorted_col, ln_gamma, ln_beta, h_ln);

    // out(f32) = relu(h_ln(bf16) @ ffn_w + b)
    gemm_mfma<false, true, false><<<((N_NODES + 127) / 128) * 2, 256, 0, stream>>>(
        h_ln, Ft, ffn_b, nullptr, out, nullptr, nullptr, N_NODES);
}

// Round 7
// 249.342 us; speedup vs baseline: 2.6430x; 1.1088x over previous
//
#include <hip/hip_runtime.h>
#include <hip/hip_bf16.h>

#define N_NODES 50000
#define E_EDGES 400000
#define IN_CH   256
#define HEADS   4
#define OUT_CH  64
#define HID     256
#define ALPHA   0.2f
#define LN_EPS  1e-5f

using f32x16 = __attribute__((ext_vector_type(16))) float;
using bf16x8 = __attribute__((ext_vector_type(8))) short;   // 8 bf16 (4 VGPRs)
using u16x8  = __attribute__((ext_vector_type(8))) unsigned short;
using u16x4  = __attribute__((ext_vector_type(4))) unsigned short;

typedef __attribute__((address_space(3))) void* lds_vp;
typedef const __attribute__((address_space(1))) void* gbl_vp;

__device__ __forceinline__ unsigned short f2bf(float f) {
    __hip_bfloat16 b = __float2bfloat16(f);
    return *(unsigned short*)&b;
}
__device__ __forceinline__ float bf2f(unsigned short u) {
    __hip_bfloat16 b = *(__hip_bfloat16*)&u;
    return __bfloat162float(b);
}

// ------------------------------------------------------------------ prep
// Wt[n][k] = bf16(W[k][n]); Ft[n][k] = bf16(ffn_w[k][n])
__global__ __launch_bounds__(256) void prep_kernel(
    const float* __restrict__ W, const float* __restrict__ ffn_w,
    unsigned short* __restrict__ Wt, unsigned short* __restrict__ Ft)
{
    int i = blockIdx.x * 256 + threadIdx.x;
    if (i < 65536) {
        int n = i >> 8, k = i & 255;
        Wt[i] = f2bf(W[k * 256 + n]);
    } else {
        int j = i - 65536;
        int n = j >> 8, k = j & 255;
        Ft[j] = f2bf(ffn_w[k * 256 + n]);
    }
}

// ------------------------------------------------------------------ B-resident GEMM
// C[M,256] = A[M,256] @ B, with Bt[n][k] (bf16, pre-transposed) staged ENTIRELY
// in LDS (128 KiB) once.  After one barrier, each wave independently computes a
// 32-row strip of A with mfma_f32_32x32x16_bf16 — no barriers in the K-loop,
// latency hidden by free-running waves.
// LDS swizzle: 16B-chunk c' of row n holds global chunk c'^(n&31); fragment
// reads then hit 32 distinct chunks per half-wave (bank-conflict floor).
// Strip mapping strip = wid*256 + blockIdx.x balances 1563 strips over all
// 256 CUs (6-7 active waves per block) instead of saturating 196 CUs.
template<bool A_IS_F32, bool RELU_BIAS>
__global__ __launch_bounds__(512, 2) void gemm_bres(
    const void* __restrict__ Av, const unsigned short* __restrict__ Bt,
    const float* __restrict__ bias, void* __restrict__ Cv, int M)
{
    __shared__ unsigned short Bs[256 * 256];   // 128 KiB

    const int tid = threadIdx.x;
    const int lane = tid & 63, wid = tid >> 6;

    // ---- stage all of B: linear LDS dest, inverse-swizzled global source
    #pragma unroll
    for (int i = 0; i < 16; i++) {
        int d = i * 512 + tid;                 // 16B-chunk id, 0..8191
        int n = d >> 5, cp = d & 31;
        int cs = cp ^ (n & 31);
        const unsigned short* g = Bt + (size_t)n * 256 + cs * 8;
        __builtin_amdgcn_global_load_lds((gbl_vp)g, (lds_vp)&Bs[(size_t)d * 8],
                                         16, 0, 0);
    }
    __syncthreads();

    const int strip = wid * 256 + blockIdx.x;  // interleaved for CU balance
    const int r0 = strip * 32;
    if (r0 >= M) return;

    const int q5 = lane & 31, kg = lane >> 5;
    const int rowc = min(r0 + q5, M - 1);      // clamped for tail strip

    f32x16 acc[8] = {};

    const float* Af = (const float*)Av;
    const unsigned short* Ab = (const unsigned short*)Av;

    // A-fragment source for k-step t: elems [t*16 + kg*8, +8) of row rowc
    float4 ra0, ra1; u16x8 rab;
    if (A_IS_F32) {
        const float* p = Af + (size_t)rowc * 256 + kg * 8;
        ra0 = *(const float4*)p; ra1 = *(const float4*)(p + 4);
    } else {
        rab = *(const u16x8*)(Ab + (size_t)rowc * 256 + kg * 8);
    }

    #pragma unroll 2
    for (int t = 0; t < 16; t++) {
        float4 nb0, nb1; u16x8 nbb;
        if (t + 1 < 16) {
            if (A_IS_F32) {
                const float* p = Af + (size_t)rowc * 256 + (t + 1) * 16 + kg * 8;
                nb0 = *(const float4*)p; nb1 = *(const float4*)(p + 4);
            } else {
                nbb = *(const u16x8*)(Ab + (size_t)rowc * 256 + (t + 1) * 16 + kg * 8);
            }
        }
        bf16x8 af;
        if (A_IS_F32) {
            union { unsigned int u[4]; bf16x8 v; } cv;
            cv.u[0] = (unsigned)f2bf(ra0.x) | ((unsigned)f2bf(ra0.y) << 16);
            cv.u[1] = (unsigned)f2bf(ra0.z) | ((unsigned)f2bf(ra0.w) << 16);
            cv.u[2] = (unsigned)f2bf(ra1.x) | ((unsigned)f2bf(ra1.y) << 16);
            cv.u[3] = (unsigned)f2bf(ra1.z) | ((unsigned)f2bf(ra1.w) << 16);
            af = cv.v;
        } else {
            union { u16x8 u; bf16x8 v; } cv; cv.u = rab; af = cv.v;
        }
        #pragma unroll
        for (int n = 0; n < 8; n++) {
            // B fragment: col = q5 (row n*32+q5 of Bt), k-chunk t*2+kg, swizzled
            const bf16x8 bf = *(const bf16x8*)((const char*)Bs +
                (size_t)(n * 32 + q5) * 512 + (((t * 2 + kg) ^ q5) * 16));
            acc[n] = __builtin_amdgcn_mfma_f32_32x32x16_bf16(af, bf, acc[n], 0, 0, 0);
        }
        ra0 = nb0; ra1 = nb1; rab = nbb;
    }

    // ---- epilogue.  D layout: col = lane&31, row = (reg&3)+8*(reg>>2)+4*kg
    #pragma unroll
    for (int n = 0; n < 8; n++) {
        int gc = n * 32 + q5;
        float bv = RELU_BIAS ? bias[gc] : 0.f;
        #pragma unroll
        for (int reg = 0; reg < 16; reg++) {
            int rl = (reg & 3) + 8 * (reg >> 2) + 4 * kg;
            int gr = r0 + rl;
            if (gr >= M) continue;
            float v = acc[n][reg];
            if (RELU_BIAS) {
                v += bv; v = v > 0.f ? v : 0.f;
                ((float*)Cv)[(size_t)gr * 256 + gc] = v;
            } else {
                ((unsigned short*)Cv)[(size_t)gr * 256 + gc] = f2bf(v);
            }
        }
    }
}

// ------------------------------------------------------------------ scores
// one wave per node; lane owns 4 cols.  s = dot(Wh[n,h,:], a_src/dst[h,:])
__global__ __launch_bounds__(256) void scores_kernel(
    const unsigned short* __restrict__ Wh, const float* __restrict__ attn_fc,
    float* __restrict__ s_src, float* __restrict__ s_dst)
{
    const int lane = threadIdx.x & 63, wid = threadIdx.x >> 6;
    const int n = blockIdx.x * 4 + wid;
    const int h = lane >> 4;
    const int d0 = 4 * (lane & 15);
    u16x4 w = *(const u16x4*)(Wh + (size_t)n * HID + 4 * lane);
    float ps = 0.f, pd = 0.f;
    #pragma unroll
    for (int q = 0; q < 4; q++) {
        float wf = bf2f(w[q]);
        ps += wf * attn_fc[h * 128 + d0 + q];
        pd += wf * attn_fc[h * 128 + 64 + d0 + q];
    }
    #pragma unroll
    for (int off = 8; off; off >>= 1) {
        ps += __shfl_xor(ps, off, 16);
        pd += __shfl_xor(pd, off, 16);
    }
    if ((lane & 15) == 0) {
        s_src[n * HEADS + h] = ps;
        s_dst[n * HEADS + h] = pd;
    }
}

// ------------------------------------------------------------------ histogram
__global__ void hist_kernel(const int* __restrict__ erow, int* __restrict__ counts) {
    int e = blockIdx.x * blockDim.x + threadIdx.x;
    if (e < E_EDGES) atomicAdd(&counts[erow[e]], 1);
}

// ------------------------------------------------------------------ 3-pass scan
__global__ __launch_bounds__(256) void scanA_kernel(
    const int* __restrict__ counts, int* __restrict__ bsum)
{
    const int b = blockIdx.x, tid = threadIdx.x;
    int i0 = b * 512 + tid;
    int v = 0;
    if (i0 < N_NODES) v += counts[i0];
    if (i0 + 256 < N_NODES) v += counts[i0 + 256];
    #pragma unroll
    for (int off = 32; off; off >>= 1) v += __shfl_xor(v, off, 64);
    __shared__ int ws[4];
    if ((tid & 63) == 0) ws[tid >> 6] = v;
    __syncthreads();
    if (tid == 0) bsum[b] = ws[0] + ws[1] + ws[2] + ws[3];
}

__global__ __launch_bounds__(128) void scanB_kernel(
    const int* __restrict__ bsum, int* __restrict__ bscan, int nb)
{
    const int tid = threadIdx.x;
    const int lane = tid & 63, wid = tid >> 6;
    int val = (tid < nb) ? bsum[tid] : 0;
    int x = val;
    #pragma unroll
    for (int off = 1; off < 64; off <<= 1) {
        int y = __shfl_up(x, off, 64);
        if (lane >= off) x += y;
    }
    __shared__ int w0;
    if (tid == 63) w0 = x;
    __syncthreads();
    if (wid == 1) x += w0;
    if (tid < nb) bscan[tid] = x - val;
}

__global__ __launch_bounds__(512) void scanC_kernel(
    const int* __restrict__ counts, const int* __restrict__ bscan,
    int* __restrict__ offsets, int* __restrict__ cursor)
{
    const int b = blockIdx.x, tid = threadIdx.x;
    const int lane = tid & 63, wid = tid >> 6;
    const int i = b * 512 + tid;
    int v = (i < N_NODES) ? counts[i] : 0;
    int x = v;
    #pragma unroll
    for (int off = 1; off < 64; off <<= 1) {
        int y = __shfl_up(x, off, 64);
        if (lane >= off) x += y;
    }
    __shared__ int ws[8];
    if (lane == 63) ws[wid] = x;
    __syncthreads();
    if (wid == 0 && lane < 8) {
        int s = ws[lane];
        #pragma unroll
        for (int off = 1; off < 8; off <<= 1) {
            int y = __shfl_up(s, off, 8);
            if ((lane & 7) >= off) s += y;
        }
        ws[lane] = s;
    }
    __syncthreads();
    int prefix = (wid ? ws[wid - 1] : 0) + bscan[b];
    int excl = prefix + x - v;
    if (i < N_NODES) { offsets[i] = excl; cursor[i] = excl; }
    if (i == N_NODES - 1) offsets[N_NODES] = excl + v;
}

// ------------------------------------------------------------------ scatter + weight precompute
// w[e,h] = exp(leaky(s_src[row]+s_dst[col]))  (global-max term cancels in alpha)
__global__ __launch_bounds__(256) void scatter_kernel(
    const int* __restrict__ erow, const int* __restrict__ ecol,
    const float* __restrict__ s_src, const float* __restrict__ s_dst,
    int* __restrict__ cursor, int* __restrict__ sorted_col,
    float4* __restrict__ sorted_w)
{
    int e = blockIdx.x * blockDim.x + threadIdx.x;
    if (e >= E_EDGES) return;
    int r = erow[e], c = ecol[e];
    float4 ss = ((const float4*)s_src)[r];
    float4 sd = ((const float4*)s_dst)[c];
    float sc[4] = {ss.x + sd.x, ss.y + sd.y, ss.z + sd.z, ss.w + sd.w};
    float4 w;
    float* wp = (float*)&w;
    #pragma unroll
    for (int h = 0; h < 4; h++) {
        float v = sc[h] > 0.f ? sc[h] : ALPHA * sc[h];
        wp[h] = __expf(v);
    }
    int pos = atomicAdd(&cursor[r], 1);
    sorted_col[pos] = c;
    sorted_w[pos] = w;
}

// ------------------------------------------------------------------ aggregate + residual + LN
// one wave per node, TWO edges in parallel: lanes 0-31 = even edge, 32-63 = odd
// edge; each lane owns 8 cols (u16x8 16B gather).  Parity partial sums combined
// with one shfl_xor(32) at the end.
__global__ __launch_bounds__(256) void aggregate_ln_kernel(
    const unsigned short* __restrict__ Wh, const float* __restrict__ sorted_w,
    const int* __restrict__ offsets, const int* __restrict__ sorted_col,
    const float* __restrict__ ln_gamma, const float* __restrict__ ln_beta,
    unsigned short* __restrict__ h_ln)
{
    const int lane = threadIdx.x & 63, wid = threadIdx.x >> 6;
    const int n = blockIdx.x * 4 + wid;
    const int p = lane >> 5;
    const int q5 = lane & 31;
    const int c0 = q5 * 8;
    const int h = q5 >> 3;
    const int beg = offsets[n], end = offsets[n + 1];

    float acc[8] = {};
    float wsum = 0.f;
    for (int base = beg; base < end; base += 64) {
        int cnt = min(64, end - base);
        int cv = (base + lane < end) ? sorted_col[base + lane] : 0;
        int jj = 0;
        #pragma unroll 2
        for (; jj + 2 <= cnt; jj += 2) {
            int c = __shfl(cv, jj + p, 64);
            float w = sorted_w[(size_t)(base + jj + p) * 4 + h];
            u16x8 r = *(const u16x8*)(Wh + (size_t)c * HID + c0);
            wsum += w;
            #pragma unroll
            for (int k = 0; k < 8; k++) acc[k] += w * bf2f(r[k]);
        }
        if (jj < cnt) {                        // odd tail edge: half-wave 0 only
            int c = __shfl(cv, jj, 64);
            if (p == 0) {
                float w = sorted_w[(size_t)(base + jj) * 4 + h];
                u16x8 r = *(const u16x8*)(Wh + (size_t)c * HID + c0);
                wsum += w;
                #pragma unroll
                for (int k = 0; k < 8; k++) acc[k] += w * bf2f(r[k]);
            }
        }
    }
    // combine edge-parity halves (both halves then hold identical full sums)
    wsum += __shfl_xor(wsum, 32, 64);
    #pragma unroll
    for (int k = 0; k < 8; k++) acc[k] += __shfl_xor(acc[k], 32, 64);

    u16x8 rr = *(const u16x8*)(Wh + (size_t)n * HID + c0);
    float inv_w = 1.f / (wsum + 1e-15f);
    float val[8];
    float s = 0.f;
    #pragma unroll
    for (int k = 0; k < 8; k++) {
        val[k] = acc[k] * inv_w + bf2f(rr[k]);
        s += val[k];
    }
    #pragma unroll
    for (int off = 16; off; off >>= 1) s += __shfl_xor(s, off, 64);  // within 32-group
    float mu = s * (1.f / HID);
    float s2 = 0.f;
    #pragma unroll
    for (int k = 0; k < 8; k++) { float d = val[k] - mu; s2 += d * d; }
    #pragma unroll
    for (int off = 16; off; off >>= 1) s2 += __shfl_xor(s2, off, 64);
    float inv_std = rsqrtf(s2 * (1.f / HID) + LN_EPS);

    if (p == 0) {
        float4 g0 = *(const float4*)(ln_gamma + c0);
        float4 g1 = *(const float4*)(ln_gamma + c0 + 4);
        float4 b0 = *(const float4*)(ln_beta + c0);
        float4 b1 = *(const float4*)(ln_beta + c0 + 4);
        u16x8 outv;
        outv[0] = f2bf((val[0] - mu) * inv_std * g0.x + b0.x);
        outv[1] = f2bf((val[1] - mu) * inv_std * g0.y + b0.y);
        outv[2] = f2bf((val[2] - mu) * inv_std * g0.z + b0.z);
        outv[3] = f2bf((val[3] - mu) * inv_std * g0.w + b0.w);
        outv[4] = f2bf((val[4] - mu) * inv_std * g1.x + b1.x);
        outv[5] = f2bf((val[5] - mu) * inv_std * g1.y + b1.y);
        outv[6] = f2bf((val[6] - mu) * inv_std * g1.z + b1.z);
        outv[7] = f2bf((val[7] - mu) * inv_std * g1.w + b1.w);
        *(u16x8*)(h_ln + (size_t)n * HID + c0) = outv;
    }
}

// ------------------------------------------------------------------ launch
extern "C" void kernel_launch(void* const* d_in, const int* in_sizes, int n_in,
                              void* d_out, int out_size, void* d_ws, size_t ws_size,
                              hipStream_t stream)
{
    const float* h        = (const float*)d_in[0];
    const int*   erow     = (const int*)  d_in[1];
    const int*   ecol     = (const int*)  d_in[2];
    const float* W        = (const float*)d_in[3];
    const float* attn_fc  = (const float*)d_in[4];
    const float* ln_gamma = (const float*)d_in[5];
    const float* ln_beta  = (const float*)d_in[6];
    const float* ffn_w    = (const float*)d_in[7];
    const float* ffn_b    = (const float*)d_in[8];
    float* out = (float*)d_out;

    // workspace layout (16B-aligned)
    unsigned short* Wh   = (unsigned short*)d_ws;            // N*HID bf16
    unsigned short* h_ln = Wh + (size_t)N_NODES * HID;       // N*HID bf16
    unsigned short* Wt   = h_ln + (size_t)N_NODES * HID;     // 256*256 bf16
    unsigned short* Ft   = Wt + 65536;                       // 256*256 bf16
    float* s_src  = (float*)(Ft + 65536);                    // N*HEADS
    float* s_dst  = s_src + N_NODES * HEADS;                 // N*HEADS
    float* sorted_w = s_dst + N_NODES * HEADS;               // E*HEADS
    int*   counts = (int*)(sorted_w + (size_t)E_EDGES * HEADS); // N
    int*   offsets = counts + N_NODES;                       // N+1
    int*   cursor  = offsets + N_NODES + 1;                  // N
    int*   sorted_col = cursor + N_NODES;                    // E
    int*   bsum   = sorted_col + E_EDGES;                    // 128
    int*   bscan  = bsum + 128;                              // 128

    const int NB = (N_NODES + 511) / 512;                    // 98

    hipMemsetAsync(counts, 0, N_NODES * sizeof(int), stream);
    prep_kernel<<<512, 256, 0, stream>>>(W, ffn_w, Wt, Ft);

    // Wh(bf16) = h(f32) @ W
    gemm_bres<true, false><<<256, 512, 0, stream>>>(h, Wt, nullptr, Wh, N_NODES);

    scores_kernel<<<N_NODES / 4, 256, 0, stream>>>(Wh, attn_fc, s_src, s_dst);
    hist_kernel<<<(E_EDGES + 255) / 256, 256, 0, stream>>>(erow, counts);
    scanA_kernel<<<NB, 256, 0, stream>>>(counts, bsum);
    scanB_kernel<<<1, 128, 0, stream>>>(bsum, bscan, NB);
    scanC_kernel<<<NB, 512, 0, stream>>>(counts, bscan, offsets, cursor);
    scatter_kernel<<<(E_EDGES + 255) / 256, 256, 0, stream>>>(
        erow, ecol, s_src, s_dst, cursor, sorted_col, (float4*)sorted_w);
    aggregate_ln_kernel<<<N_NODES / 4, 256, 0, stream>>>(
        Wh, sorted_w, offsets, sorted_col, ln_gamma, ln_beta, h_ln);

    // out(f32) = relu(h_ln(bf16) @ ffn_w + b)
    gemm_bres<false, true><<<256, 512, 0, stream>>>(h_ln, Ft, ffn_b, out, N_NODES);
}